// Round 1
// baseline (2637.933 us; speedup 1.0000x reference)
//
#include <hip/hip_runtime.h>
#include <stdint.h>

typedef unsigned int uint;

#define A2B   1.8897259886f
#define R_MIN (0.5f * A2B)
#define R_MAX (4.0f * A2B)

// ---------------------------------------------------------------------------
// K1: per-edge filter MLP + atomic scatter of messages into agg[src][16]
// ---------------------------------------------------------------------------
__global__ void __launch_bounds__(256) k_edge(
        const int* __restrict__ src, const int* __restrict__ tgt,
        const float* __restrict__ dist, const int* __restrict__ elem,
        const float* __restrict__ embed,
        const float* __restrict__ fw1, const float* __restrict__ fb1,
        const float* __restrict__ fw2, const float* __restrict__ fb2,
        float* __restrict__ agg, int E)
{
    __shared__ float s_fw1[256], s_fw2[256], s_fb1[16], s_fb2[16], s_emb[64];
    int tid = threadIdx.x;
    s_fw1[tid] = fw1[tid];
    s_fw2[tid] = fw2[tid];
    if (tid < 16) { s_fb1[tid] = fb1[tid]; s_fb2[tid] = fb2[tid]; }
    if (tid < 64) s_emb[tid] = embed[tid];
    __syncthreads();

    int e = blockIdx.x * 256 + tid;
    if (e >= E) return;

    float d = dist[e];
    const float step = (R_MAX - R_MIN) / 15.0f;   // linspace spacing (16 pts)
    const float invw = 16.0f / (R_MAX - R_MIN);   // 1 / RBF_WIDTH
    float rbf[16];
    #pragma unroll
    for (int k = 0; k < 16; ++k) {
        float t = (d - (R_MIN + (float)k * step)) * invw;
        rbf[k] = __expf(-0.5f * t * t);
    }
    float hid[16];
    #pragma unroll
    for (int i = 0; i < 16; ++i) {
        float a = s_fb1[i];
        #pragma unroll
        for (int k = 0; k < 16; ++k) a += rbf[k] * s_fw1[i * 16 + k];
        hid[i] = a / (1.0f + __expf(-a));         // silu
    }
    int s = src[e];
    int q = elem[tgt[e]];
    float* ag = agg + (size_t)s * 16;
    const float* er = s_emb + q * 16;
    #pragma unroll
    for (int j = 0; j < 16; ++j) {
        float w = s_fb2[j];
        #pragma unroll
        for (int i = 0; i < 16; ++i) w += hid[i] * s_fw2[j * 16 + i];
        atomicAdd(ag + j, w * er[j]);
    }
}

// ---------------------------------------------------------------------------
// K2: per-node h = embed + agg; VQ argmin over the 4 owned codes; loss reduce
// ---------------------------------------------------------------------------
__global__ void __launch_bounds__(256) k_node(
        const int* __restrict__ elem, const float* __restrict__ embed,
        const float* __restrict__ codebook, const float* __restrict__ agg,
        int* __restrict__ atype, float* __restrict__ loss, int N)
{
    __shared__ float s_cb[256], s_cbn[16], s_emb[64];
    __shared__ float s_red[4];
    int tid = threadIdx.x;
    s_cb[tid] = codebook[tid];
    if (tid < 64) s_emb[tid] = embed[tid];
    __syncthreads();
    if (tid < 16) {
        float s = 0.f;
        #pragma unroll
        for (int j = 0; j < 16; ++j) { float c = s_cb[tid * 16 + j]; s += c * c; }
        s_cbn[tid] = s;
    }
    __syncthreads();

    int n = blockIdx.x * 256 + tid;
    float lp = 0.0f;
    if (n < N) {
        int q = elem[n];
        const float4* ap = (const float4*)(agg + (size_t)n * 16);
        float h[16];
        #pragma unroll
        for (int v = 0; v < 4; ++v) {
            float4 f = ap[v];
            h[v*4+0] = f.x; h[v*4+1] = f.y; h[v*4+2] = f.z; h[v*4+3] = f.w;
        }
        #pragma unroll
        for (int j = 0; j < 16; ++j) h[j] += s_emb[q * 16 + j];
        float hh = 0.f;
        #pragma unroll
        for (int j = 0; j < 16; ++j) hh += h[j] * h[j];
        // match reference's expanded-form d2 = |h|^2 - 2 h.c + |c|^2
        float best = __builtin_inff(); int bi = 0;
        #pragma unroll
        for (int c = 0; c < 4; ++c) {
            int code = q * 4 + c;
            float dot = 0.f;
            #pragma unroll
            for (int j = 0; j < 16; ++j) dot += h[j] * s_cb[code * 16 + j];
            float d2 = hh - 2.0f * dot + s_cbn[code];
            if (d2 < best) { best = d2; bi = code; }   // strict < keeps first min
        }
        atype[n] = bi;
        #pragma unroll
        for (int j = 0; j < 16; ++j) {
            float df = h[j] - s_cb[bi * 16 + j];
            lp += df * df;
        }
    }
    // block reduction of loss partials
    #pragma unroll
    for (int o = 32; o > 0; o >>= 1) lp += __shfl_down(lp, o, 64);
    int wid = tid >> 6;
    if ((tid & 63) == 0) s_red[wid] = lp;
    __syncthreads();
    if (tid == 0) atomicAdd(loss, s_red[0] + s_red[1] + s_red[2] + s_red[3]);
}

// ---------------------------------------------------------------------------
// K2b: build the 2560-entry (combo x pair) output table; finalize vq_loss
// ---------------------------------------------------------------------------
__global__ void __launch_bounds__(256) k_table(
        const float* __restrict__ codebook,
        const float* __restrict__ mw1, const float* __restrict__ mb1,
        const float* __restrict__ mw2, const float* __restrict__ mb2,
        const float* __restrict__ rD, const float* __restrict__ rA,
        const float* __restrict__ rR,
        const float* __restrict__ loss, float4* __restrict__ table,
        float* __restrict__ out_loss, float inv_nd)
{
    __shared__ float s_cb[256], s_mw1[256], s_mb1[16], s_mw2[48], s_mb2[3];
    __shared__ float s_rd[10], s_ra[10], s_rr[10];
    int tid = threadIdx.x;
    s_cb[tid] = codebook[tid];
    s_mw1[tid] = mw1[tid];
    if (tid < 16) s_mb1[tid] = mb1[tid];
    if (tid < 48) s_mw2[tid] = mw2[tid];
    if (tid < 3)  s_mb2[tid] = mb2[tid];
    if (tid < 10) { s_rd[tid] = rD[tid]; s_ra[tid] = rA[tid]; s_rr[tid] = rR[tid]; }
    __syncthreads();

    int a = tid >> 4, b = tid & 15;
    float pf[16];
    #pragma unroll
    for (int j = 0; j < 16; ++j) pf[j] = s_cb[a * 16 + j] + s_cb[b * 16 + j];
    float hid[16];
    #pragma unroll
    for (int i = 0; i < 16; ++i) {
        float acc = s_mb1[i];
        #pragma unroll
        for (int j = 0; j < 16; ++j) acc += pf[j] * s_mw1[i * 16 + j];
        hid[i] = acc / (1.0f + __expf(-acc));
    }
    float del[3];
    #pragma unroll
    for (int r = 0; r < 3; ++r) {
        float acc = s_mb2[r];
        #pragma unroll
        for (int i = 0; i < 16; ++i) acc += hid[i] * s_mw2[r * 16 + i];
        del[r] = acc;
    }
    #pragma unroll
    for (int p = 0; p < 10; ++p) {
        float xd = s_rd[p] + del[0];
        float xa = s_ra[p] + del[1];
        float De = (xd > 20.f) ? xd : log1pf(__expf(xd));   // softplus
        float al = (xa > 20.f) ? xa : log1pf(__expf(xa));
        float r0 = s_rr[p] + del[2];
        table[tid * 10 + p] = make_float4(De, al, r0, 0.f);
    }
    if (tid == 0) out_loss[0] = 0.25f * loss[0] * inv_nd;
}

// ---------------------------------------------------------------------------
// K3: per-edge output = table[(at[src]*16 + at[tgt])*10 + pair_idx]
// ---------------------------------------------------------------------------
__global__ void __launch_bounds__(256) k_out(
        const int* __restrict__ src, const int* __restrict__ tgt,
        const int* __restrict__ pidx, const int* __restrict__ atype,
        const float4* __restrict__ table, float2* __restrict__ out, int Ehalf)
{
    int i = blockIdx.x * 256 + threadIdx.x;
    if (i >= Ehalf) return;
    int2 s2 = ((const int2*)src)[i];
    int2 t2 = ((const int2*)tgt)[i];
    int2 p2 = ((const int2*)pidx)[i];
    int i0 = (atype[s2.x] * 16 + atype[t2.x]) * 10 + p2.x;
    int i1 = (atype[s2.y] * 16 + atype[t2.y]) * 10 + p2.y;
    float4 t0 = table[i0];
    float4 t1 = table[i1];
    float2* op = out + (size_t)3 * i;
    op[0] = make_float2(t0.x, t0.y);
    op[1] = make_float2(t0.z, t1.x);
    op[2] = make_float2(t1.y, t1.z);
}

// ---------------------------------------------------------------------------
extern "C" void kernel_launch(void* const* d_in, const int* in_sizes, int n_in,
                              void* d_out, int out_size, void* d_ws, size_t ws_size,
                              hipStream_t stream)
{
    (void)n_in; (void)out_size;
    const int*   elem  = (const int*)d_in[0];
    const int*   eidx  = (const int*)d_in[1];
    const float* dist  = (const float*)d_in[2];
    const int*   pidx  = (const int*)d_in[3];
    const float* embed = (const float*)d_in[4];
    const float* fw1   = (const float*)d_in[5];
    const float* fb1   = (const float*)d_in[6];
    const float* fw2   = (const float*)d_in[7];
    const float* fb2   = (const float*)d_in[8];
    const float* mw1   = (const float*)d_in[9];
    const float* mb1   = (const float*)d_in[10];
    const float* mw2   = (const float*)d_in[11];
    const float* mb2   = (const float*)d_in[12];
    const float* cb    = (const float*)d_in[13];
    const float* rD    = (const float*)d_in[14];
    const float* rA    = (const float*)d_in[15];
    const float* rR    = (const float*)d_in[16];

    int N = in_sizes[0];
    int E = in_sizes[2];
    const int* src = eidx;
    const int* tgt = eidx + E;

    char* ws = (char*)d_ws;
    size_t aggB = (size_t)N * 16 * sizeof(float);
    float*  agg   = (float*)ws;
    float*  loss  = (float*)(ws + aggB);
    int*    atype = (int*)(ws + aggB + 64);
    float4* table = (float4*)(ws + aggB + 64 + (size_t)N * 4);
    size_t need = aggB + 64 + (size_t)N * 4 + 2560 * sizeof(float4);
    if (ws_size < need) return;  // scratch too small: fail loudly via validation

    hipMemsetAsync(d_ws, 0, aggB + 64, stream);

    k_edge<<<(E + 255) / 256, 256, 0, stream>>>(src, tgt, dist, elem, embed,
                                                fw1, fb1, fw2, fb2, agg, E);
    k_node<<<(N + 255) / 256, 256, 0, stream>>>(elem, embed, cb, agg, atype, loss, N);
    float* outl = (float*)d_out + (size_t)3 * E;
    k_table<<<1, 256, 0, stream>>>(cb, mw1, mb1, mw2, mb2, rD, rA, rR,
                                   loss, table, outl,
                                   1.0f / (float)((size_t)N * 16));
    k_out<<<(E / 2 + 255) / 256, 256, 0, stream>>>(src, tgt, pidx, atype, table,
                                                   (float2*)d_out, E / 2);
}

// Round 2
// 902.495 us; speedup vs baseline: 2.9229x; 2.9229x over previous
//
#include <hip/hip_runtime.h>
#include <stdint.h>

#define A2B   1.8897259886f
#define R_MIN (0.5f * A2B)
#define R_MAX (4.0f * A2B)

// ---------------------------------------------------------------------------
// K1: per-edge rank assignment (one int atomic per edge) + pack target-elem q
// ---------------------------------------------------------------------------
__global__ void __launch_bounds__(256) k_rank(
        const int* __restrict__ src, const int* __restrict__ tgt,
        const int* __restrict__ elem, int* __restrict__ deg,
        unsigned short* __restrict__ packed, int E)
{
    int e = blockIdx.x * 256 + threadIdx.x;
    if (e >= E) return;
    int s = src[e];
    int q = elem[tgt[e]];
    int r = atomicAdd(deg + s, 1);          // rank of this edge within its src
    packed[e] = (unsigned short)(r | (q << 14));   // rank < 16384 guaranteed
}

// ---------------------------------------------------------------------------
// K2a/b/c: exclusive scan of deg[N] -> offs[N+1]
// ---------------------------------------------------------------------------
__global__ void __launch_bounds__(256) k_scan1(
        const int* __restrict__ deg, int* __restrict__ offs,
        int* __restrict__ bsum, int N)
{
    __shared__ int sd[256];
    int t = threadIdx.x, i = blockIdx.x * 256 + t;
    int v = (i < N) ? deg[i] : 0;
    sd[t] = v; __syncthreads();
    #pragma unroll
    for (int o = 1; o < 256; o <<= 1) {
        int x = (t >= o) ? sd[t - o] : 0;
        __syncthreads();
        sd[t] += x;
        __syncthreads();
    }
    if (i < N) offs[i] = sd[t] - v;                 // exclusive
    if (t == 255) bsum[blockIdx.x] = sd[255];       // block total
}

__global__ void __launch_bounds__(512) k_scan2(int* __restrict__ bsum, int NB)
{
    __shared__ int sd[512];
    int t = threadIdx.x;
    int v = (t < NB) ? bsum[t] : 0;
    sd[t] = v; __syncthreads();
    #pragma unroll
    for (int o = 1; o < 512; o <<= 1) {
        int x = (t >= o) ? sd[t - o] : 0;
        __syncthreads();
        sd[t] += x;
        __syncthreads();
    }
    if (t < NB) bsum[t] = sd[t] - v;                // exclusive block bases
}

__global__ void __launch_bounds__(256) k_scan3(
        int* __restrict__ offs, const int* __restrict__ bsum, int N, int E)
{
    int i = blockIdx.x * 256 + threadIdx.x;
    if (i < N) offs[i] += bsum[i >> 8];
    else if (i == N) offs[N] = E;
}

// ---------------------------------------------------------------------------
// K3: scatter 8B payload (dist, q) to CSR slot  [payload lives in d_out]
// ---------------------------------------------------------------------------
__global__ void __launch_bounds__(256) k_scatter(
        const int* __restrict__ src, const float* __restrict__ dist,
        const unsigned short* __restrict__ packed, const int* __restrict__ offs,
        float2* __restrict__ payload, int E)
{
    int e = blockIdx.x * 256 + threadIdx.x;
    if (e >= E) return;
    unsigned p = packed[e];
    int pos = offs[src[e]] + (int)(p & 0x3FFF);
    payload[pos] = make_float2(dist[e], __int_as_float((int)(p >> 14)));
}

// ---------------------------------------------------------------------------
// K4: per-node gather: edge MLP + accumulate + VQ argmin + loss  (fused)
// ---------------------------------------------------------------------------
__global__ void __launch_bounds__(256) k_gather(
        const int* __restrict__ elem, const float* __restrict__ embed,
        const float* __restrict__ codebook,
        const float* __restrict__ fw1, const float* __restrict__ fb1,
        const float* __restrict__ fw2, const float* __restrict__ fb2,
        const int* __restrict__ offs, const float2* __restrict__ payload,
        int* __restrict__ atype, float* __restrict__ loss, int N)
{
    __shared__ float s_fw1[256], s_fw2[256], s_cb[256];
    __shared__ float s_fb1[16], s_fb2[16], s_emb[64], s_cbn[16];
    __shared__ float s_red[4];
    int t = threadIdx.x;
    s_fw1[t] = fw1[t];
    s_fw2[t] = fw2[t];
    s_cb[t]  = codebook[t];
    if (t < 16) { s_fb1[t] = fb1[t]; s_fb2[t] = fb2[t]; }
    if (t < 64) s_emb[t] = embed[t];
    __syncthreads();
    if (t < 16) {
        float s = 0.f;
        #pragma unroll
        for (int j = 0; j < 16; ++j) { float c = s_cb[t * 16 + j]; s += c * c; }
        s_cbn[t] = s;
    }
    __syncthreads();

    int n = blockIdx.x * 256 + t;
    float lp = 0.0f;
    if (n < N) {
        int o0 = offs[n], o1 = offs[n + 1];
        float acc[16];
        #pragma unroll
        for (int j = 0; j < 16; ++j) acc[j] = 0.f;

        const float step = (R_MAX - R_MIN) / 15.0f;
        const float invw = 16.0f / (R_MAX - R_MIN);
        for (int i = o0; i < o1; ++i) {
            float2 pl = payload[i];
            float d = pl.x;
            int q = __float_as_int(pl.y);
            float rbf[16];
            #pragma unroll
            for (int k = 0; k < 16; ++k) {
                float u = (d - (R_MIN + (float)k * step)) * invw;
                rbf[k] = __expf(-0.5f * u * u);
            }
            float hid[16];
            #pragma unroll
            for (int i2 = 0; i2 < 16; ++i2) {
                float a = s_fb1[i2];
                #pragma unroll
                for (int k = 0; k < 16; ++k) a += rbf[k] * s_fw1[i2 * 16 + k];
                hid[i2] = a / (1.0f + __expf(-a));      // silu
            }
            const float* er = s_emb + q * 16;
            #pragma unroll
            for (int j = 0; j < 16; ++j) {
                float w = s_fb2[j];
                #pragma unroll
                for (int i2 = 0; i2 < 16; ++i2) w += hid[i2] * s_fw2[j * 16 + i2];
                acc[j] += w * er[j];                    // message = h[tgt] * W
            }
        }
        int qn = elem[n];
        float h[16], hh = 0.f;
        #pragma unroll
        for (int j = 0; j < 16; ++j) {
            h[j] = acc[j] + s_emb[qn * 16 + j];
            hh += h[j] * h[j];
        }
        float best = __builtin_inff(); int bi = 0;
        #pragma unroll
        for (int c = 0; c < 4; ++c) {
            int code = qn * 4 + c;
            float dot = 0.f;
            #pragma unroll
            for (int j = 0; j < 16; ++j) dot += h[j] * s_cb[code * 16 + j];
            float d2 = hh - 2.0f * dot + s_cbn[code];
            if (d2 < best) { best = d2; bi = code; }
        }
        atype[n] = bi;
        #pragma unroll
        for (int j = 0; j < 16; ++j) {
            float df = h[j] - s_cb[bi * 16 + j];
            lp += df * df;
        }
    }
    #pragma unroll
    for (int o = 32; o > 0; o >>= 1) lp += __shfl_down(lp, o, 64);
    int wid = t >> 6;
    if ((t & 63) == 0) s_red[wid] = lp;
    __syncthreads();
    if (t == 0) atomicAdd(loss, s_red[0] + s_red[1] + s_red[2] + s_red[3]);
}

// ---------------------------------------------------------------------------
// K5: build the 2560-entry (combo x pair) output table; finalize vq_loss
// ---------------------------------------------------------------------------
__global__ void __launch_bounds__(256) k_table(
        const float* __restrict__ codebook,
        const float* __restrict__ mw1, const float* __restrict__ mb1,
        const float* __restrict__ mw2, const float* __restrict__ mb2,
        const float* __restrict__ rD, const float* __restrict__ rA,
        const float* __restrict__ rR,
        const float* __restrict__ loss, float4* __restrict__ table,
        float* __restrict__ out_loss, float inv_nd)
{
    __shared__ float s_cb[256], s_mw1[256], s_mb1[16], s_mw2[48], s_mb2[3];
    __shared__ float s_rd[10], s_ra[10], s_rr[10];
    int tid = threadIdx.x;
    s_cb[tid] = codebook[tid];
    s_mw1[tid] = mw1[tid];
    if (tid < 16) s_mb1[tid] = mb1[tid];
    if (tid < 48) s_mw2[tid] = mw2[tid];
    if (tid < 3)  s_mb2[tid] = mb2[tid];
    if (tid < 10) { s_rd[tid] = rD[tid]; s_ra[tid] = rA[tid]; s_rr[tid] = rR[tid]; }
    __syncthreads();

    int a = tid >> 4, b = tid & 15;
    float pf[16];
    #pragma unroll
    for (int j = 0; j < 16; ++j) pf[j] = s_cb[a * 16 + j] + s_cb[b * 16 + j];
    float hid[16];
    #pragma unroll
    for (int i = 0; i < 16; ++i) {
        float acc = s_mb1[i];
        #pragma unroll
        for (int j = 0; j < 16; ++j) acc += pf[j] * s_mw1[i * 16 + j];
        hid[i] = acc / (1.0f + __expf(-acc));
    }
    float del[3];
    #pragma unroll
    for (int r = 0; r < 3; ++r) {
        float acc = s_mb2[r];
        #pragma unroll
        for (int i = 0; i < 16; ++i) acc += hid[i] * s_mw2[r * 16 + i];
        del[r] = acc;
    }
    #pragma unroll
    for (int p = 0; p < 10; ++p) {
        float xd = s_rd[p] + del[0];
        float xa = s_ra[p] + del[1];
        float De = (xd > 20.f) ? xd : log1pf(__expf(xd));   // softplus
        float al = (xa > 20.f) ? xa : log1pf(__expf(xa));
        float r0 = s_rr[p] + del[2];
        table[tid * 10 + p] = make_float4(De, al, r0, 0.f);
    }
    if (tid == 0) out_loss[0] = 0.25f * loss[0] * inv_nd;
}

// ---------------------------------------------------------------------------
// K6: per-edge output = table[(at[src]*16 + at[tgt])*10 + pair_idx]
// ---------------------------------------------------------------------------
__global__ void __launch_bounds__(256) k_out(
        const int* __restrict__ src, const int* __restrict__ tgt,
        const int* __restrict__ pidx, const int* __restrict__ atype,
        const float4* __restrict__ table, float2* __restrict__ out, int Ehalf)
{
    int i = blockIdx.x * 256 + threadIdx.x;
    if (i >= Ehalf) return;
    int2 s2 = ((const int2*)src)[i];
    int2 t2 = ((const int2*)tgt)[i];
    int2 p2 = ((const int2*)pidx)[i];
    int i0 = (atype[s2.x] * 16 + atype[t2.x]) * 10 + p2.x;
    int i1 = (atype[s2.y] * 16 + atype[t2.y]) * 10 + p2.y;
    float4 t0 = table[i0];
    float4 t1 = table[i1];
    float2* op = out + (size_t)3 * i;
    op[0] = make_float2(t0.x, t0.y);
    op[1] = make_float2(t0.z, t1.x);
    op[2] = make_float2(t1.y, t1.z);
}

// ---------------------------------------------------------------------------
extern "C" void kernel_launch(void* const* d_in, const int* in_sizes, int n_in,
                              void* d_out, int out_size, void* d_ws, size_t ws_size,
                              hipStream_t stream)
{
    (void)n_in; (void)out_size;
    const int*   elem  = (const int*)d_in[0];
    const int*   eidx  = (const int*)d_in[1];
    const float* dist  = (const float*)d_in[2];
    const int*   pidx  = (const int*)d_in[3];
    const float* embed = (const float*)d_in[4];
    const float* fw1   = (const float*)d_in[5];
    const float* fb1   = (const float*)d_in[6];
    const float* fw2   = (const float*)d_in[7];
    const float* fb2   = (const float*)d_in[8];
    const float* mw1   = (const float*)d_in[9];
    const float* mb1   = (const float*)d_in[10];
    const float* mw2   = (const float*)d_in[11];
    const float* mb2   = (const float*)d_in[12];
    const float* cb    = (const float*)d_in[13];
    const float* rD    = (const float*)d_in[14];
    const float* rA    = (const float*)d_in[15];
    const float* rR    = (const float*)d_in[16];

    int N = in_sizes[0];
    int E = in_sizes[2];
    const int* src = eidx;
    const int* tgt = eidx + E;
    int NB = (N + 255) / 256;
    if (NB > 512) return;                       // scan assumes <=512 blocks

    // ---- workspace layout ----
    char* ws = (char*)d_ws;
    size_t cur = 0;
    int*   deg   = (int*)(ws + cur);  cur += (size_t)N * 4;
    float* loss  = (float*)(ws + cur); cur += 4;           // memset with deg
    size_t clearB = cur;
    int*   offs  = (int*)(ws + cur);  cur += (size_t)(N + 1) * 4;
    int*   bsum  = (int*)(ws + cur);  cur += 512 * 4;
    int*   atype = (int*)(ws + cur);  cur += (size_t)N * 4;
    unsigned short* packed = (unsigned short*)(ws + cur); cur += (size_t)E * 2;
    cur = (cur + 15) & ~(size_t)15;
    float4* table = (float4*)(ws + cur); cur += 2560 * sizeof(float4);
    if (ws_size < cur) return;

    float2* payload = (float2*)d_out;           // 25.6MB scratch inside d_out

    hipMemsetAsync(d_ws, 0, clearB, stream);    // deg + loss

    k_rank<<<(E + 255) / 256, 256, 0, stream>>>(src, tgt, elem, deg, packed, E);
    k_scan1<<<NB, 256, 0, stream>>>(deg, offs, bsum, N);
    k_scan2<<<1, 512, 0, stream>>>(bsum, NB);
    k_scan3<<<(N + 256) / 256, 256, 0, stream>>>(offs, bsum, N, E);
    k_scatter<<<(E + 255) / 256, 256, 0, stream>>>(src, dist, packed, offs,
                                                   payload, E);
    k_gather<<<NB, 256, 0, stream>>>(elem, embed, cb, fw1, fb1, fw2, fb2,
                                     offs, payload, atype, loss, N);
    float* outl = (float*)d_out + (size_t)3 * E;
    k_table<<<1, 256, 0, stream>>>(cb, mw1, mb1, mw2, mb2, rD, rA, rR,
                                   loss, table, outl,
                                   1.0f / (float)((size_t)N * 16));
    k_out<<<(E / 2 + 255) / 256, 256, 0, stream>>>(src, tgt, pidx, atype, table,
                                                   (float2*)d_out, E / 2);
}

// Round 3
// 817.679 us; speedup vs baseline: 3.2261x; 1.1037x over previous
//
#include <hip/hip_runtime.h>
#include <stdint.h>

#define A2B   1.8897259886f
#define R_MIN (0.5f * A2B)
#define R_MAX (4.0f * A2B)

#define GCAP 9216   // staged edges per 256-node block (mean 8192, sd ~90)

// ---------------------------------------------------------------------------
// K1: per-edge rank assignment (one int atomic per edge) + pack target-elem q
// ---------------------------------------------------------------------------
__global__ void __launch_bounds__(256) k_rank(
        const int* __restrict__ src, const int* __restrict__ tgt,
        const int* __restrict__ elem, int* __restrict__ deg,
        unsigned short* __restrict__ packed, int E)
{
    int e = blockIdx.x * 256 + threadIdx.x;
    if (e >= E) return;
    int s = src[e];
    int q = elem[tgt[e]];
    int r = atomicAdd(deg + s, 1);          // rank of this edge within its src
    packed[e] = (unsigned short)(r | (q << 14));   // rank < 16384 guaranteed
}

// ---------------------------------------------------------------------------
// K2a/b/c: exclusive scan of deg[N] -> offs[N+1]
// ---------------------------------------------------------------------------
__global__ void __launch_bounds__(256) k_scan1(
        const int* __restrict__ deg, int* __restrict__ offs,
        int* __restrict__ bsum, int N)
{
    __shared__ int sd[256];
    int t = threadIdx.x, i = blockIdx.x * 256 + t;
    int v = (i < N) ? deg[i] : 0;
    sd[t] = v; __syncthreads();
    #pragma unroll
    for (int o = 1; o < 256; o <<= 1) {
        int x = (t >= o) ? sd[t - o] : 0;
        __syncthreads();
        sd[t] += x;
        __syncthreads();
    }
    if (i < N) offs[i] = sd[t] - v;                 // exclusive
    if (t == 255) bsum[blockIdx.x] = sd[255];       // block total
}

__global__ void __launch_bounds__(512) k_scan2(int* __restrict__ bsum, int NB)
{
    __shared__ int sd[512];
    int t = threadIdx.x;
    int v = (t < NB) ? bsum[t] : 0;
    sd[t] = v; __syncthreads();
    #pragma unroll
    for (int o = 1; o < 512; o <<= 1) {
        int x = (t >= o) ? sd[t - o] : 0;
        __syncthreads();
        sd[t] += x;
        __syncthreads();
    }
    if (t < NB) bsum[t] = sd[t] - v;                // exclusive block bases
}

__global__ void __launch_bounds__(256) k_scan3(
        int* __restrict__ offs, const int* __restrict__ bsum, int N, int E)
{
    int i = blockIdx.x * 256 + threadIdx.x;
    if (i < N) offs[i] += bsum[i >> 8];
    else if (i == N) offs[N] = E;
}

// ---------------------------------------------------------------------------
// K3: scatter 8B payload (dist, q) to CSR slot  [payload lives in d_out]
// ---------------------------------------------------------------------------
__global__ void __launch_bounds__(256) k_scatter(
        const int* __restrict__ src, const float* __restrict__ dist,
        const unsigned short* __restrict__ packed, const int* __restrict__ offs,
        float2* __restrict__ payload, int E)
{
    int e = blockIdx.x * 256 + threadIdx.x;
    if (e >= E) return;
    unsigned p = packed[e];
    int pos = offs[src[e]] + (int)(p & 0x3FFF);
    payload[pos] = make_float2(dist[e], __int_as_float((int)(p >> 14)));
}

// ---------------------------------------------------------------------------
// K4: per-node gather with LDS-staged payload segment (coalesced), fused VQ
// ---------------------------------------------------------------------------
__device__ __forceinline__ int swz(int i) { return i ^ ((i >> 5) & 15); }

__global__ void __launch_bounds__(256) k_gather(
        const int* __restrict__ elem, const float* __restrict__ embed,
        const float* __restrict__ codebook,
        const float* __restrict__ fw1, const float* __restrict__ fb1,
        const float* __restrict__ fw2, const float* __restrict__ fb2,
        const int* __restrict__ offs, const float2* __restrict__ payload,
        int* __restrict__ atype, float* __restrict__ loss, int N)
{
    extern __shared__ float2 s_pay[];               // GCAP entries (dynamic)
    __shared__ float s_fw1[256], s_fw2[256], s_cb[256];
    __shared__ float s_fb1[16], s_fb2[16], s_emb[64], s_cbn[16];
    __shared__ float s_red[4];
    int t = threadIdx.x;
    s_fw1[t] = fw1[t];
    s_fw2[t] = fw2[t];
    s_cb[t]  = codebook[t];
    if (t < 16) { s_fb1[t] = fb1[t]; s_fb2[t] = fb2[t]; }
    if (t < 64) s_emb[t] = embed[t];
    __syncthreads();
    if (t < 16) {
        float s = 0.f;
        #pragma unroll
        for (int j = 0; j < 16; ++j) { float c = s_cb[t * 16 + j]; s += c * c; }
        s_cbn[t] = s;
    }

    int n0 = blockIdx.x * 256;
    int nEnd = (n0 + 256 < N) ? n0 + 256 : N;
    int seg0 = offs[n0];
    int seg1 = offs[nEnd];
    int cnt = seg1 - seg0;
    bool use_lds = (cnt <= GCAP);
    if (use_lds) {
        for (int i = t; i < cnt; i += 256)
            s_pay[swz(i)] = payload[seg0 + i];      // coalesced read, swz write
    }
    __syncthreads();

    int n = n0 + t;
    float lp = 0.0f;
    if (n < N) {
        int o0 = offs[n], o1 = offs[n + 1];
        float acc[16];
        #pragma unroll
        for (int j = 0; j < 16; ++j) acc[j] = 0.f;

        const float step = (R_MAX - R_MIN) / 15.0f;
        const float invw = 16.0f / (R_MAX - R_MIN);
        for (int i = o0; i < o1; ++i) {
            float2 pl = use_lds ? s_pay[swz(i - seg0)] : payload[i];
            float d = pl.x;
            int q = __float_as_int(pl.y);
            float rbf[16];
            #pragma unroll
            for (int k = 0; k < 16; ++k) {
                float u = (d - (R_MIN + (float)k * step)) * invw;
                rbf[k] = __expf(-0.5f * u * u);
            }
            float hid[16];
            #pragma unroll
            for (int i2 = 0; i2 < 16; ++i2) {
                float a = s_fb1[i2];
                #pragma unroll
                for (int k = 0; k < 16; ++k) a += rbf[k] * s_fw1[i2 * 16 + k];
                hid[i2] = a / (1.0f + __expf(-a));      // silu
            }
            const float* er = s_emb + q * 16;
            #pragma unroll
            for (int j = 0; j < 16; ++j) {
                float w = s_fb2[j];
                #pragma unroll
                for (int i2 = 0; i2 < 16; ++i2) w += hid[i2] * s_fw2[j * 16 + i2];
                acc[j] += w * er[j];                    // message = h[tgt] * W
            }
        }
        int qn = elem[n];
        float h[16], hh = 0.f;
        #pragma unroll
        for (int j = 0; j < 16; ++j) {
            h[j] = acc[j] + s_emb[qn * 16 + j];
            hh += h[j] * h[j];
        }
        float best = __builtin_inff(); int bi = 0;
        #pragma unroll
        for (int c = 0; c < 4; ++c) {
            int code = qn * 4 + c;
            float dot = 0.f;
            #pragma unroll
            for (int j = 0; j < 16; ++j) dot += h[j] * s_cb[code * 16 + j];
            float d2 = hh - 2.0f * dot + s_cbn[code];
            if (d2 < best) { best = d2; bi = code; }
        }
        atype[n] = bi;
        #pragma unroll
        for (int j = 0; j < 16; ++j) {
            float df = h[j] - s_cb[bi * 16 + j];
            lp += df * df;
        }
    }
    #pragma unroll
    for (int o = 32; o > 0; o >>= 1) lp += __shfl_down(lp, o, 64);
    int wid = t >> 6;
    if ((t & 63) == 0) s_red[wid] = lp;
    __syncthreads();
    if (t == 0) atomicAdd(loss, s_red[0] + s_red[1] + s_red[2] + s_red[3]);
}

// ---------------------------------------------------------------------------
// K5: build the 2560-entry (combo x pair) output table; finalize vq_loss
// ---------------------------------------------------------------------------
__global__ void __launch_bounds__(256) k_table(
        const float* __restrict__ codebook,
        const float* __restrict__ mw1, const float* __restrict__ mb1,
        const float* __restrict__ mw2, const float* __restrict__ mb2,
        const float* __restrict__ rD, const float* __restrict__ rA,
        const float* __restrict__ rR,
        const float* __restrict__ loss, float4* __restrict__ table,
        float* __restrict__ out_loss, float inv_nd)
{
    __shared__ float s_cb[256], s_mw1[256], s_mb1[16], s_mw2[48], s_mb2[3];
    __shared__ float s_rd[10], s_ra[10], s_rr[10];
    int tid = threadIdx.x;
    s_cb[tid] = codebook[tid];
    s_mw1[tid] = mw1[tid];
    if (tid < 16) s_mb1[tid] = mb1[tid];
    if (tid < 48) s_mw2[tid] = mw2[tid];
    if (tid < 3)  s_mb2[tid] = mb2[tid];
    if (tid < 10) { s_rd[tid] = rD[tid]; s_ra[tid] = rA[tid]; s_rr[tid] = rR[tid]; }
    __syncthreads();

    int a = tid >> 4, b = tid & 15;
    float pf[16];
    #pragma unroll
    for (int j = 0; j < 16; ++j) pf[j] = s_cb[a * 16 + j] + s_cb[b * 16 + j];
    float hid[16];
    #pragma unroll
    for (int i = 0; i < 16; ++i) {
        float acc = s_mb1[i];
        #pragma unroll
        for (int j = 0; j < 16; ++j) acc += pf[j] * s_mw1[i * 16 + j];
        hid[i] = acc / (1.0f + __expf(-acc));
    }
    float del[3];
    #pragma unroll
    for (int r = 0; r < 3; ++r) {
        float acc = s_mb2[r];
        #pragma unroll
        for (int i = 0; i < 16; ++i) acc += hid[i] * s_mw2[r * 16 + i];
        del[r] = acc;
    }
    #pragma unroll
    for (int p = 0; p < 10; ++p) {
        float xd = s_rd[p] + del[0];
        float xa = s_ra[p] + del[1];
        float De = (xd > 20.f) ? xd : log1pf(__expf(xd));   // softplus
        float al = (xa > 20.f) ? xa : log1pf(__expf(xa));
        float r0 = s_rr[p] + del[2];
        table[tid * 10 + p] = make_float4(De, al, r0, 0.f);
    }
    if (tid == 0) out_loss[0] = 0.25f * loss[0] * inv_nd;
}

// ---------------------------------------------------------------------------
// K6: per-edge output = table[(at[src]*16 + at[tgt])*10 + pair_idx]
// ---------------------------------------------------------------------------
__global__ void __launch_bounds__(256) k_out(
        const int* __restrict__ src, const int* __restrict__ tgt,
        const int* __restrict__ pidx, const int* __restrict__ atype,
        const float4* __restrict__ table, float2* __restrict__ out, int Ehalf)
{
    int i = blockIdx.x * 256 + threadIdx.x;
    if (i >= Ehalf) return;
    int2 s2 = ((const int2*)src)[i];
    int2 t2 = ((const int2*)tgt)[i];
    int2 p2 = ((const int2*)pidx)[i];
    int i0 = (atype[s2.x] * 16 + atype[t2.x]) * 10 + p2.x;
    int i1 = (atype[s2.y] * 16 + atype[t2.y]) * 10 + p2.y;
    float4 t0 = table[i0];
    float4 t1 = table[i1];
    float2* op = out + (size_t)3 * i;
    op[0] = make_float2(t0.x, t0.y);
    op[1] = make_float2(t0.z, t1.x);
    op[2] = make_float2(t1.y, t1.z);
}

// ---------------------------------------------------------------------------
extern "C" void kernel_launch(void* const* d_in, const int* in_sizes, int n_in,
                              void* d_out, int out_size, void* d_ws, size_t ws_size,
                              hipStream_t stream)
{
    (void)n_in; (void)out_size;
    const int*   elem  = (const int*)d_in[0];
    const int*   eidx  = (const int*)d_in[1];
    const float* dist  = (const float*)d_in[2];
    const int*   pidx  = (const int*)d_in[3];
    const float* embed = (const float*)d_in[4];
    const float* fw1   = (const float*)d_in[5];
    const float* fb1   = (const float*)d_in[6];
    const float* fw2   = (const float*)d_in[7];
    const float* fb2   = (const float*)d_in[8];
    const float* mw1   = (const float*)d_in[9];
    const float* mb1   = (const float*)d_in[10];
    const float* mw2   = (const float*)d_in[11];
    const float* mb2   = (const float*)d_in[12];
    const float* cb    = (const float*)d_in[13];
    const float* rD    = (const float*)d_in[14];
    const float* rA    = (const float*)d_in[15];
    const float* rR    = (const float*)d_in[16];

    int N = in_sizes[0];
    int E = in_sizes[2];
    const int* src = eidx;
    const int* tgt = eidx + E;
    int NB = (N + 255) / 256;
    if (NB > 512) return;                       // scan assumes <=512 blocks

    // ---- workspace layout ----
    char* ws = (char*)d_ws;
    size_t cur = 0;
    int*   deg   = (int*)(ws + cur);  cur += (size_t)N * 4;
    float* loss  = (float*)(ws + cur); cur += 4;           // memset with deg
    size_t clearB = cur;
    int*   offs  = (int*)(ws + cur);  cur += (size_t)(N + 1) * 4;
    int*   bsum  = (int*)(ws + cur);  cur += 512 * 4;
    int*   atype = (int*)(ws + cur);  cur += (size_t)N * 4;
    unsigned short* packed = (unsigned short*)(ws + cur); cur += (size_t)E * 2;
    cur = (cur + 15) & ~(size_t)15;
    float4* table = (float4*)(ws + cur); cur += 2560 * sizeof(float4);
    if (ws_size < cur) return;

    float2* payload = (float2*)d_out;           // 25.6MB scratch inside d_out

    hipMemsetAsync(d_ws, 0, clearB, stream);    // deg + loss

    k_rank<<<(E + 255) / 256, 256, 0, stream>>>(src, tgt, elem, deg, packed, E);
    k_scan1<<<NB, 256, 0, stream>>>(deg, offs, bsum, N);
    k_scan2<<<1, 512, 0, stream>>>(bsum, NB);
    k_scan3<<<(N + 256) / 256, 256, 0, stream>>>(offs, bsum, N, E);
    k_scatter<<<(E + 255) / 256, 256, 0, stream>>>(src, dist, packed, offs,
                                                   payload, E);
    k_gather<<<NB, 256, (size_t)GCAP * sizeof(float2), stream>>>(
                                     elem, embed, cb, fw1, fb1, fw2, fb2,
                                     offs, payload, atype, loss, N);
    float* outl = (float*)d_out + (size_t)3 * E;
    k_table<<<1, 256, 0, stream>>>(cb, mw1, mb1, mw2, mb2, rD, rA, rR,
                                   loss, table, outl,
                                   1.0f / (float)((size_t)N * 16));
    k_out<<<(E / 2 + 255) / 256, 256, 0, stream>>>(src, tgt, pidx, atype, table,
                                                   (float2*)d_out, E / 2);
}